// Round 2
// baseline (1788.575 us; speedup 1.0000x reference)
//
#include <hip/hip_runtime.h>

#define N_NODES 20000
#define N_EDGES 640000
#define D 128
#define TM 64   // GEMM tile rows per block

// ---------------- CSR build ----------------

__global__ void zero_counts_kernel(int* counts) {
    int i = blockIdx.x * blockDim.x + threadIdx.x;
    if (i < N_NODES) counts[i] = 0;
}

__global__ void count_deg_kernel(const int4* __restrict__ dst4, int* __restrict__ counts) {
    int e4 = blockIdx.x * blockDim.x + threadIdx.x;
    if (e4 < N_EDGES / 4) {
        int4 d = dst4[e4];
        atomicAdd(&counts[d.x], 1);
        atomicAdd(&counts[d.y], 1);
        atomicAdd(&counts[d.z], 1);
        atomicAdd(&counts[d.w], 1);
    }
}

// Single-block exclusive scan over 20000 degree counts -> offsets, and init cursor.
__global__ __launch_bounds__(1024) void scan_offsets_kernel(const int* __restrict__ counts,
                                                            int* __restrict__ offsets,
                                                            int* __restrict__ cursor) {
    __shared__ int partial[1024];
    int t = threadIdx.x;
    const int CH = (N_NODES + 1023) / 1024;  // 20 nodes per thread
    int lo = t * CH;
    int hi = lo + CH; if (hi > N_NODES) hi = N_NODES;
    int s = 0;
    for (int i = lo; i < hi; ++i) s += counts[i];
    partial[t] = s;
    __syncthreads();
    for (int off = 1; off < 1024; off <<= 1) {
        int v = (t >= off) ? partial[t - off] : 0;
        __syncthreads();
        partial[t] += v;
        __syncthreads();
    }
    int run = (t == 0) ? 0 : partial[t - 1];
    for (int i = lo; i < hi; ++i) {
        int c = counts[i];
        offsets[i] = run;
        cursor[i]  = run;
        run += c;
    }
    if (t == 1023) offsets[N_NODES] = run;  // == N_EDGES
}

__global__ void scatter_edges_kernel(const int4* __restrict__ src4, const int4* __restrict__ dst4,
                                     int* __restrict__ cursor, int* __restrict__ srcsort) {
    int e4 = blockIdx.x * blockDim.x + threadIdx.x;
    if (e4 < N_EDGES / 4) {
        int4 s = src4[e4];
        int4 d = dst4[e4];
        srcsort[atomicAdd(&cursor[d.x], 1)] = s.x;
        srcsort[atomicAdd(&cursor[d.y], 1)] = s.y;
        srcsort[atomicAdd(&cursor[d.z], 1)] = s.z;
        srcsort[atomicAdd(&cursor[d.w], 1)] = s.w;
    }
}

// ---------------- per-layer: aggregation  x[i] = h[i] + sum_{j->i} h[j] ----------------
// 128 threads = 4 edge-slots x 32 lanes, float4 per lane (one 512B row per slot).

__global__ __launch_bounds__(128) void agg_kernel(const float* __restrict__ hin,
                                                  const int* __restrict__ offsets,
                                                  const int* __restrict__ srcsort,
                                                  float* __restrict__ x) {
    __shared__ float red[32 * 4];
    int node = blockIdx.x;
    int t = threadIdx.x;
    int slot = t >> 5;   // 0..3
    int lane = t & 31;   // col-group of 4 floats
    int lo = offsets[node];
    int hi = offsets[node + 1];

    float4 acc = make_float4(0.f, 0.f, 0.f, 0.f);
    for (int k = lo + slot; k < hi; k += 4) {
        int s = srcsort[k];  // uniform within slot -> broadcast
        float4 v = *((const float4*)&hin[(size_t)s * D + lane * 4]);
        acc.x += v.x; acc.y += v.y; acc.z += v.z; acc.w += v.w;
    }

    // pair slots within each wave (lane ^ 32)
    acc.x += __shfl_xor(acc.x, 32);
    acc.y += __shfl_xor(acc.y, 32);
    acc.z += __shfl_xor(acc.z, 32);
    acc.w += __shfl_xor(acc.w, 32);

    if (t >= 64 && t < 96) {  // wave1 (slots 2+3) lanes 0-31 hold wave1 sum
        *((float4*)&red[lane * 4]) = acc;
    }
    __syncthreads();
    if (t < 32) {  // wave0 lanes 0-31 hold slots0+1 sum
        float4 o = *((const float4*)&red[lane * 4]);
        float4 sv = *((const float4*)&hin[(size_t)node * D + lane * 4]);
        o.x += acc.x + sv.x;
        o.y += acc.y + sv.y;
        o.z += acc.z + sv.z;
        o.w += acc.w + sv.w;
        *((float4*)&x[(size_t)node * D + lane * 4]) = o;
    }
}

// ---------------- per-layer: out = x @ W + b  (x: N x 128, W: 128 x 128) ----------------

__global__ __launch_bounds__(256) void gemm_kernel(const float* __restrict__ x,
                                                   const float* __restrict__ W,
                                                   const float* __restrict__ bias,
                                                   float* __restrict__ out) {
    __shared__ float Xs[TM][D];  // 32 KB
    int t = threadIdx.x;
    int row0 = blockIdx.x * TM;
    int nrows = N_NODES - row0; if (nrows > TM) nrows = TM;

    for (int i = t; i < nrows * (D / 4); i += 256) {
        int r  = i / (D / 4);
        int c4 = i % (D / 4);
        ((float4*)&Xs[r][0])[c4] = ((const float4*)&x[(size_t)(row0 + r) * D])[c4];
    }
    __syncthreads();

    int cg = t & 31;   // 32 col-groups of 4 cols
    int rg = t >> 5;   // 8 row-groups of 8 rows
    int j0 = cg * 4;
    int r0 = rg * 8;

    float acc[8][4];
    float4 bb = *((const float4*)&bias[j0]);
    #pragma unroll
    for (int i = 0; i < 8; ++i) {
        acc[i][0] = bb.x; acc[i][1] = bb.y; acc[i][2] = bb.z; acc[i][3] = bb.w;
    }

    for (int k4 = 0; k4 < D; k4 += 4) {
        float4 xv[8];
        #pragma unroll
        for (int i = 0; i < 8; ++i)
            xv[i] = *((const float4*)&Xs[r0 + i][k4]);   // ds_read_b128
        #pragma unroll
        for (int kk = 0; kk < 4; ++kk) {
            float4 w = *((const float4*)&W[(k4 + kk) * D + j0]);  // L2-hot, coalesced
            #pragma unroll
            for (int i = 0; i < 8; ++i) {
                float c = (kk == 0) ? xv[i].x : (kk == 1) ? xv[i].y
                        : (kk == 2) ? xv[i].z : xv[i].w;
                acc[i][0] += c * w.x;
                acc[i][1] += c * w.y;
                acc[i][2] += c * w.z;
                acc[i][3] += c * w.w;
            }
        }
    }

    #pragma unroll
    for (int i = 0; i < 8; ++i) {
        int r = r0 + i;
        if (r < nrows) {
            *((float4*)&out[(size_t)(row0 + r) * D + j0]) =
                make_float4(acc[i][0], acc[i][1], acc[i][2], acc[i][3]);
        }
    }
}

// ---------------- launch ----------------

extern "C" void kernel_launch(void* const* d_in, const int* in_sizes, int n_in,
                              void* d_out, int out_size, void* d_ws, size_t ws_size,
                              hipStream_t stream) {
    const float* h   = (const float*)d_in[0];
    const int*   ei  = (const int*)d_in[1];
    const int*   src = ei;
    const int*   dst = ei + N_EDGES;
    const float* Wm[4] = {(const float*)d_in[2], (const float*)d_in[4],
                          (const float*)d_in[6], (const float*)d_in[8]};
    const float* Bv[4] = {(const float*)d_in[3], (const float*)d_in[5],
                          (const float*)d_in[7], (const float*)d_in[9]};
    float* out = (float*)d_out;

    char* ws = (char*)d_ws;
    auto alloc = [&](size_t bytes) {
        char* p = ws;
        ws += (bytes + 255) & ~(size_t)255;
        return p;
    };
    int*   counts  = (int*)alloc(N_NODES * sizeof(int));
    int*   offsets = (int*)alloc((N_NODES + 1) * sizeof(int));
    int*   cursor  = (int*)alloc(N_NODES * sizeof(int));
    int*   srcsort = (int*)alloc(N_EDGES * sizeof(int));
    float* bufA    = (float*)alloc((size_t)N_NODES * D * sizeof(float));
    float* bufB    = (float*)alloc((size_t)N_NODES * D * sizeof(float));

    zero_counts_kernel<<<(N_NODES + 255) / 256, 256, 0, stream>>>(counts);
    count_deg_kernel<<<(N_EDGES / 4 + 255) / 256, 256, 0, stream>>>((const int4*)dst, counts);
    scan_offsets_kernel<<<1, 1024, 0, stream>>>(counts, offsets, cursor);
    scatter_edges_kernel<<<(N_EDGES / 4 + 255) / 256, 256, 0, stream>>>(
        (const int4*)src, (const int4*)dst, cursor, srcsort);

    const float* cur = h;
    for (int l = 0; l < 4; ++l) {
        agg_kernel<<<N_NODES, 128, 0, stream>>>(cur, offsets, srcsort, bufA);
        float* o = (l == 3) ? out : bufB;
        gemm_kernel<<<(N_NODES + TM - 1) / TM, 256, 0, stream>>>(bufA, Wm[l], Bv[l], o);
        cur = o;
    }
}

// Round 3
// 424.419 us; speedup vs baseline: 4.2142x; 4.2142x over previous
//
#include <hip/hip_runtime.h>

#define N_NODES 20000
#define N_EDGES 640000
#define D 128
#define TM 64   // GEMM tile rows per block

// ---------------- CSR build ----------------

__global__ void zero_counts_kernel(int* counts) {
    int i = blockIdx.x * blockDim.x + threadIdx.x;
    if (i < N_NODES) counts[i] = 0;
}

__global__ void count_deg_kernel(const int4* __restrict__ dst4, int* __restrict__ counts) {
    int e4 = blockIdx.x * blockDim.x + threadIdx.x;
    if (e4 < N_EDGES / 4) {
        int4 d = dst4[e4];
        atomicAdd(&counts[d.x], 1);
        atomicAdd(&counts[d.y], 1);
        atomicAdd(&counts[d.z], 1);
        atomicAdd(&counts[d.w], 1);
    }
}

// Single-block exclusive scan over 20000 degree counts -> offsets, and init cursor.
__global__ __launch_bounds__(1024) void scan_offsets_kernel(const int* __restrict__ counts,
                                                            int* __restrict__ offsets,
                                                            int* __restrict__ cursor) {
    __shared__ int partial[1024];
    int t = threadIdx.x;
    const int CH = (N_NODES + 1023) / 1024;  // 20 nodes per thread
    int lo = t * CH;
    int hi = lo + CH; if (hi > N_NODES) hi = N_NODES;
    int s = 0;
    for (int i = lo; i < hi; ++i) s += counts[i];
    partial[t] = s;
    __syncthreads();
    for (int off = 1; off < 1024; off <<= 1) {
        int v = (t >= off) ? partial[t - off] : 0;
        __syncthreads();
        partial[t] += v;
        __syncthreads();
    }
    int run = (t == 0) ? 0 : partial[t - 1];
    for (int i = lo; i < hi; ++i) {
        int c = counts[i];
        offsets[i] = run;
        cursor[i]  = run;
        run += c;
    }
    if (t == 1023) offsets[N_NODES] = run;  // == N_EDGES
}

__global__ void scatter_edges_kernel(const int4* __restrict__ src4, const int4* __restrict__ dst4,
                                     int* __restrict__ cursor, int* __restrict__ srcsort) {
    int e4 = blockIdx.x * blockDim.x + threadIdx.x;
    if (e4 < N_EDGES / 4) {
        int4 s = src4[e4];
        int4 d = dst4[e4];
        srcsort[atomicAdd(&cursor[d.x], 1)] = s.x;
        srcsort[atomicAdd(&cursor[d.y], 1)] = s.y;
        srcsort[atomicAdd(&cursor[d.z], 1)] = s.z;
        srcsort[atomicAdd(&cursor[d.w], 1)] = s.w;
    }
}

// ---------------- per-layer: aggregation  x[i] = h[i] + sum_{j->i} h[j] ----------------
// 128 threads = 4 edge-slots x 32 lanes, float4 per lane (one 512B row per slot).

__global__ __launch_bounds__(128) void agg_kernel(const float* __restrict__ hin,
                                                  const int* __restrict__ offsets,
                                                  const int* __restrict__ srcsort,
                                                  float* __restrict__ x) {
    __shared__ float red[32 * 4];
    int node = blockIdx.x;
    int t = threadIdx.x;
    int slot = t >> 5;   // 0..3
    int lane = t & 31;   // col-group of 4 floats
    int lo = offsets[node];
    int hi = offsets[node + 1];

    float4 acc = make_float4(0.f, 0.f, 0.f, 0.f);
    for (int k = lo + slot; k < hi; k += 4) {
        int s = srcsort[k];  // uniform within slot -> broadcast
        float4 v = *((const float4*)&hin[(size_t)s * D + lane * 4]);
        acc.x += v.x; acc.y += v.y; acc.z += v.z; acc.w += v.w;
    }

    // pair slots within each wave (lane ^ 32)
    acc.x += __shfl_xor(acc.x, 32);
    acc.y += __shfl_xor(acc.y, 32);
    acc.z += __shfl_xor(acc.z, 32);
    acc.w += __shfl_xor(acc.w, 32);

    if (t >= 64 && t < 96) {  // wave1 (slots 2+3) lanes 0-31 hold wave1 sum
        *((float4*)&red[lane * 4]) = acc;
    }
    __syncthreads();
    if (t < 32) {  // wave0 lanes 0-31 hold slots0+1 sum
        float4 o = *((const float4*)&red[lane * 4]);
        float4 sv = *((const float4*)&hin[(size_t)node * D + lane * 4]);
        o.x += acc.x + sv.x;
        o.y += acc.y + sv.y;
        o.z += acc.z + sv.z;
        o.w += acc.w + sv.w;
        *((float4*)&x[(size_t)node * D + lane * 4]) = o;
    }
}

// ---------------- per-layer: out = x @ W + b  (x: N x 128, W: 128 x 128) ----------------
// All inner-loop values are NAMED SCALARS (no runtime-indexable arrays -> no scratch).

__global__ __launch_bounds__(256) void gemm_kernel(const float* __restrict__ x,
                                                   const float* __restrict__ W,
                                                   const float* __restrict__ bias,
                                                   float* __restrict__ out) {
    __shared__ float Xs[TM][D];  // 32 KB
    int t = threadIdx.x;
    int row0 = blockIdx.x * TM;
    int nrows = N_NODES - row0; if (nrows > TM) nrows = TM;

    for (int i = t; i < nrows * (D / 4); i += 256) {
        int r  = i / (D / 4);
        int c4 = i % (D / 4);
        ((float4*)&Xs[r][0])[c4] = ((const float4*)&x[(size_t)(row0 + r) * D])[c4];
    }
    __syncthreads();

    int cg = t & 31;   // 32 col-groups of 4 cols
    int rg = t >> 5;   // 8 row-groups of 8 rows
    int j0 = cg * 4;
    int r0 = rg * 8;

    float acc[8][4];
    float4 bb = *((const float4*)&bias[j0]);
    #pragma unroll
    for (int i = 0; i < 8; ++i) {
        acc[i][0] = bb.x; acc[i][1] = bb.y; acc[i][2] = bb.z; acc[i][3] = bb.w;
    }

    for (int k4 = 0; k4 < D; k4 += 4) {
        // 4 consecutive W rows, 4 cols each (coalesced across the 32 col-groups)
        float4 w0 = *((const float4*)&W[(k4 + 0) * D + j0]);
        float4 w1 = *((const float4*)&W[(k4 + 1) * D + j0]);
        float4 w2 = *((const float4*)&W[(k4 + 2) * D + j0]);
        float4 w3 = *((const float4*)&W[(k4 + 3) * D + j0]);
        #pragma unroll
        for (int i = 0; i < 8; ++i) {
            float4 xv = *((const float4*)&Xs[r0 + i][k4]);  // ds_read_b128
            acc[i][0] += xv.x * w0.x; acc[i][0] += xv.y * w1.x;
            acc[i][0] += xv.z * w2.x; acc[i][0] += xv.w * w3.x;
            acc[i][1] += xv.x * w0.y; acc[i][1] += xv.y * w1.y;
            acc[i][1] += xv.z * w2.y; acc[i][1] += xv.w * w3.y;
            acc[i][2] += xv.x * w0.z; acc[i][2] += xv.y * w1.z;
            acc[i][2] += xv.z * w2.z; acc[i][2] += xv.w * w3.z;
            acc[i][3] += xv.x * w0.w; acc[i][3] += xv.y * w1.w;
            acc[i][3] += xv.z * w2.w; acc[i][3] += xv.w * w3.w;
        }
    }

    #pragma unroll
    for (int i = 0; i < 8; ++i) {
        int r = r0 + i;
        if (r < nrows) {
            *((float4*)&out[(size_t)(row0 + r) * D + j0]) =
                make_float4(acc[i][0], acc[i][1], acc[i][2], acc[i][3]);
        }
    }
}

// ---------------- launch ----------------

extern "C" void kernel_launch(void* const* d_in, const int* in_sizes, int n_in,
                              void* d_out, int out_size, void* d_ws, size_t ws_size,
                              hipStream_t stream) {
    const float* h   = (const float*)d_in[0];
    const int*   ei  = (const int*)d_in[1];
    const int*   src = ei;
    const int*   dst = ei + N_EDGES;
    const float* Wm[4] = {(const float*)d_in[2], (const float*)d_in[4],
                          (const float*)d_in[6], (const float*)d_in[8]};
    const float* Bv[4] = {(const float*)d_in[3], (const float*)d_in[5],
                          (const float*)d_in[7], (const float*)d_in[9]};
    float* out = (float*)d_out;

    char* ws = (char*)d_ws;
    auto alloc = [&](size_t bytes) {
        char* p = ws;
        ws += (bytes + 255) & ~(size_t)255;
        return p;
    };
    int*   counts  = (int*)alloc(N_NODES * sizeof(int));
    int*   offsets = (int*)alloc((N_NODES + 1) * sizeof(int));
    int*   cursor  = (int*)alloc(N_NODES * sizeof(int));
    int*   srcsort = (int*)alloc(N_EDGES * sizeof(int));
    float* bufA    = (float*)alloc((size_t)N_NODES * D * sizeof(float));
    float* bufB    = (float*)alloc((size_t)N_NODES * D * sizeof(float));

    zero_counts_kernel<<<(N_NODES + 255) / 256, 256, 0, stream>>>(counts);
    count_deg_kernel<<<(N_EDGES / 4 + 255) / 256, 256, 0, stream>>>((const int4*)dst, counts);
    scan_offsets_kernel<<<1, 1024, 0, stream>>>(counts, offsets, cursor);
    scatter_edges_kernel<<<(N_EDGES / 4 + 255) / 256, 256, 0, stream>>>(
        (const int4*)src, (const int4*)dst, cursor, srcsort);

    const float* cur = h;
    for (int l = 0; l < 4; ++l) {
        agg_kernel<<<N_NODES, 128, 0, stream>>>(cur, offsets, srcsort, bufA);
        float* o = (l == 3) ? out : bufB;
        gemm_kernel<<<(N_NODES + TM - 1) / TM, 256, 0, stream>>>(bufA, Wm[l], Bv[l], o);
        cur = o;
    }
}

// Round 4
// 404.038 us; speedup vs baseline: 4.4268x; 1.0504x over previous
//
#include <hip/hip_runtime.h>

#define N_NODES 20000
#define N_EDGES 640000
#define D 128
#define TM 64   // GEMM tile rows per block

// ---------------- CSR build ----------------

__global__ void zero_counts_kernel(int* counts) {
    int i = blockIdx.x * blockDim.x + threadIdx.x;
    if (i < N_NODES) counts[i] = 0;
}

__global__ void count_deg_kernel(const int4* __restrict__ dst4, int* __restrict__ counts) {
    int e4 = blockIdx.x * blockDim.x + threadIdx.x;
    if (e4 < N_EDGES / 4) {
        int4 d = dst4[e4];
        atomicAdd(&counts[d.x], 1);
        atomicAdd(&counts[d.y], 1);
        atomicAdd(&counts[d.z], 1);
        atomicAdd(&counts[d.w], 1);
    }
}

// Single-block exclusive scan over 20000 degree counts -> offsets, and init cursor.
__global__ __launch_bounds__(1024) void scan_offsets_kernel(const int* __restrict__ counts,
                                                            int* __restrict__ offsets,
                                                            int* __restrict__ cursor) {
    __shared__ int partial[1024];
    int t = threadIdx.x;
    const int CH = (N_NODES + 1023) / 1024;  // 20 nodes per thread
    int lo = t * CH;
    int hi = lo + CH; if (hi > N_NODES) hi = N_NODES;
    int s = 0;
    for (int i = lo; i < hi; ++i) s += counts[i];
    partial[t] = s;
    __syncthreads();
    for (int off = 1; off < 1024; off <<= 1) {
        int v = (t >= off) ? partial[t - off] : 0;
        __syncthreads();
        partial[t] += v;
        __syncthreads();
    }
    int run = (t == 0) ? 0 : partial[t - 1];
    for (int i = lo; i < hi; ++i) {
        int c = counts[i];
        offsets[i] = run;
        cursor[i]  = run;
        run += c;
    }
    if (t == 1023) offsets[N_NODES] = run;  // == N_EDGES
}

__global__ void scatter_edges_kernel(const int4* __restrict__ src4, const int4* __restrict__ dst4,
                                     int* __restrict__ cursor, int* __restrict__ srcsort) {
    int e4 = blockIdx.x * blockDim.x + threadIdx.x;
    if (e4 < N_EDGES / 4) {
        int4 s = src4[e4];
        int4 d = dst4[e4];
        srcsort[atomicAdd(&cursor[d.x], 1)] = s.x;
        srcsort[atomicAdd(&cursor[d.y], 1)] = s.y;
        srcsort[atomicAdd(&cursor[d.z], 1)] = s.z;
        srcsort[atomicAdd(&cursor[d.w], 1)] = s.w;
    }
}

// ---------------- per-layer: aggregation  x[i] = h[i] + sum_{j->i} h[j] ----------------
// 128 threads = 4 edge-slots x 32 lanes, float4 per lane.
// Each slot keeps 4 independent accumulators with 4 gathers in flight (MLP).

__global__ __launch_bounds__(128) void agg_kernel(const float* __restrict__ hin,
                                                  const int* __restrict__ offsets,
                                                  const int* __restrict__ srcsort,
                                                  float* __restrict__ x) {
    __shared__ float red[32 * 4];
    int node = blockIdx.x;
    int t = threadIdx.x;
    int slot = t >> 5;   // 0..3
    int lane = t & 31;   // col-group of 4 floats
    int lo = offsets[node];
    int hi = offsets[node + 1];
    const float4* base = (const float4*)hin;

    float4 a0 = make_float4(0.f, 0.f, 0.f, 0.f);
    float4 a1 = a0, a2 = a0, a3 = a0;

    int k = lo + slot;
    // 4 independent gathers in flight per iteration (slot stride 4, unroll 4 -> stride 16)
    for (; k + 12 < hi; k += 16) {
        int s0 = srcsort[k];
        int s1 = srcsort[k + 4];
        int s2 = srcsort[k + 8];
        int s3 = srcsort[k + 12];
        float4 v0 = base[(size_t)s0 * 32 + lane];
        float4 v1 = base[(size_t)s1 * 32 + lane];
        float4 v2 = base[(size_t)s2 * 32 + lane];
        float4 v3 = base[(size_t)s3 * 32 + lane];
        a0.x += v0.x; a0.y += v0.y; a0.z += v0.z; a0.w += v0.w;
        a1.x += v1.x; a1.y += v1.y; a1.z += v1.z; a1.w += v1.w;
        a2.x += v2.x; a2.y += v2.y; a2.z += v2.z; a2.w += v2.w;
        a3.x += v3.x; a3.y += v3.y; a3.z += v3.z; a3.w += v3.w;
    }
    for (; k < hi; k += 4) {
        int s = srcsort[k];
        float4 v = base[(size_t)s * 32 + lane];
        a0.x += v.x; a0.y += v.y; a0.z += v.z; a0.w += v.w;
    }

    float4 acc;
    acc.x = (a0.x + a1.x) + (a2.x + a3.x);
    acc.y = (a0.y + a1.y) + (a2.y + a3.y);
    acc.z = (a0.z + a1.z) + (a2.z + a3.z);
    acc.w = (a0.w + a1.w) + (a2.w + a3.w);

    // pair slots within each wave (lane ^ 32)
    acc.x += __shfl_xor(acc.x, 32);
    acc.y += __shfl_xor(acc.y, 32);
    acc.z += __shfl_xor(acc.z, 32);
    acc.w += __shfl_xor(acc.w, 32);

    if (t >= 64 && t < 96) {  // wave1 lanes 0-31 hold slots2+3 sum
        *((float4*)&red[lane * 4]) = acc;
    }
    __syncthreads();
    if (t < 32) {  // wave0 lanes 0-31 hold slots0+1 sum
        float4 o = *((const float4*)&red[lane * 4]);
        float4 sv = *((const float4*)&hin[(size_t)node * D + lane * 4]);
        o.x += acc.x + sv.x;
        o.y += acc.y + sv.y;
        o.z += acc.z + sv.z;
        o.w += acc.w + sv.w;
        *((float4*)&x[(size_t)node * D + lane * 4]) = o;
    }
}

// ---------------- per-layer: out = x @ W + b  (x: N x 128, W: 128 x 128) ----------------
// All inner-loop values are NAMED SCALARS (no runtime-indexable arrays -> no scratch).

__global__ __launch_bounds__(256) void gemm_kernel(const float* __restrict__ x,
                                                   const float* __restrict__ W,
                                                   const float* __restrict__ bias,
                                                   float* __restrict__ out) {
    __shared__ float Xs[TM][D];  // 32 KB
    int t = threadIdx.x;
    int row0 = blockIdx.x * TM;
    int nrows = N_NODES - row0; if (nrows > TM) nrows = TM;

    for (int i = t; i < nrows * (D / 4); i += 256) {
        int r  = i / (D / 4);
        int c4 = i % (D / 4);
        ((float4*)&Xs[r][0])[c4] = ((const float4*)&x[(size_t)(row0 + r) * D])[c4];
    }
    __syncthreads();

    int cg = t & 31;   // 32 col-groups of 4 cols
    int rg = t >> 5;   // 8 row-groups of 8 rows
    int j0 = cg * 4;
    int r0 = rg * 8;

    float acc[8][4];
    float4 bb = *((const float4*)&bias[j0]);
    #pragma unroll
    for (int i = 0; i < 8; ++i) {
        acc[i][0] = bb.x; acc[i][1] = bb.y; acc[i][2] = bb.z; acc[i][3] = bb.w;
    }

    for (int k4 = 0; k4 < D; k4 += 4) {
        float4 w0 = *((const float4*)&W[(k4 + 0) * D + j0]);
        float4 w1 = *((const float4*)&W[(k4 + 1) * D + j0]);
        float4 w2 = *((const float4*)&W[(k4 + 2) * D + j0]);
        float4 w3 = *((const float4*)&W[(k4 + 3) * D + j0]);
        #pragma unroll
        for (int i = 0; i < 8; ++i) {
            float4 xv = *((const float4*)&Xs[r0 + i][k4]);  // ds_read_b128
            acc[i][0] += xv.x * w0.x; acc[i][0] += xv.y * w1.x;
            acc[i][0] += xv.z * w2.x; acc[i][0] += xv.w * w3.x;
            acc[i][1] += xv.x * w0.y; acc[i][1] += xv.y * w1.y;
            acc[i][1] += xv.z * w2.y; acc[i][1] += xv.w * w3.y;
            acc[i][2] += xv.x * w0.z; acc[i][2] += xv.y * w1.z;
            acc[i][2] += xv.z * w2.z; acc[i][2] += xv.w * w3.z;
            acc[i][3] += xv.x * w0.w; acc[i][3] += xv.y * w1.w;
            acc[i][3] += xv.z * w2.w; acc[i][3] += xv.w * w3.w;
        }
    }

    #pragma unroll
    for (int i = 0; i < 8; ++i) {
        int r = r0 + i;
        if (r < nrows) {
            *((float4*)&out[(size_t)(row0 + r) * D + j0]) =
                make_float4(acc[i][0], acc[i][1], acc[i][2], acc[i][3]);
        }
    }
}

// ---------------- launch ----------------

extern "C" void kernel_launch(void* const* d_in, const int* in_sizes, int n_in,
                              void* d_out, int out_size, void* d_ws, size_t ws_size,
                              hipStream_t stream) {
    const float* h   = (const float*)d_in[0];
    const int*   ei  = (const int*)d_in[1];
    const int*   src = ei;
    const int*   dst = ei + N_EDGES;
    const float* Wm[4] = {(const float*)d_in[2], (const float*)d_in[4],
                          (const float*)d_in[6], (const float*)d_in[8]};
    const float* Bv[4] = {(const float*)d_in[3], (const float*)d_in[5],
                          (const float*)d_in[7], (const float*)d_in[9]};
    float* out = (float*)d_out;

    char* ws = (char*)d_ws;
    auto alloc = [&](size_t bytes) {
        char* p = ws;
        ws += (bytes + 255) & ~(size_t)255;
        return p;
    };
    int*   counts  = (int*)alloc(N_NODES * sizeof(int));
    int*   offsets = (int*)alloc((N_NODES + 1) * sizeof(int));
    int*   cursor  = (int*)alloc(N_NODES * sizeof(int));
    int*   srcsort = (int*)alloc(N_EDGES * sizeof(int));
    float* bufA    = (float*)alloc((size_t)N_NODES * D * sizeof(float));
    float* bufB    = (float*)alloc((size_t)N_NODES * D * sizeof(float));

    zero_counts_kernel<<<(N_NODES + 255) / 256, 256, 0, stream>>>(counts);
    count_deg_kernel<<<(N_EDGES / 4 + 255) / 256, 256, 0, stream>>>((const int4*)dst, counts);
    scan_offsets_kernel<<<1, 1024, 0, stream>>>(counts, offsets, cursor);
    scatter_edges_kernel<<<(N_EDGES / 4 + 255) / 256, 256, 0, stream>>>(
        (const int4*)src, (const int4*)dst, cursor, srcsort);

    const float* cur = h;
    for (int l = 0; l < 4; ++l) {
        agg_kernel<<<N_NODES, 128, 0, stream>>>(cur, offsets, srcsort, bufA);
        float* o = (l == 3) ? out : bufB;
        gemm_kernel<<<(N_NODES + TM - 1) / TM, 256, 0, stream>>>(bufA, Wm[l], Bv[l], o);
        cur = o;
    }
}

// Round 5
// 381.900 us; speedup vs baseline: 4.6834x; 1.0580x over previous
//
#include <hip/hip_runtime.h>

#define N_NODES 20000
#define N_EDGES 640000
#define D 128
#define TM 64   // GEMM tile rows per block

// ---------------- CSR build ----------------

__global__ void zero_counts_kernel(int* counts) {
    int i = blockIdx.x * blockDim.x + threadIdx.x;
    if (i < N_NODES) counts[i] = 0;
}

__global__ void count_deg_kernel(const int4* __restrict__ dst4, int* __restrict__ counts) {
    int e4 = blockIdx.x * blockDim.x + threadIdx.x;
    if (e4 < N_EDGES / 4) {
        int4 d = dst4[e4];
        atomicAdd(&counts[d.x], 1);
        atomicAdd(&counts[d.y], 1);
        atomicAdd(&counts[d.z], 1);
        atomicAdd(&counts[d.w], 1);
    }
}

// Single-block exclusive scan over 20000 degree counts -> offsets, and init cursor.
__global__ __launch_bounds__(1024) void scan_offsets_kernel(const int* __restrict__ counts,
                                                            int* __restrict__ offsets,
                                                            int* __restrict__ cursor) {
    __shared__ int partial[1024];
    int t = threadIdx.x;
    const int CH = (N_NODES + 1023) / 1024;  // 20 nodes per thread
    int lo = t * CH;
    int hi = lo + CH; if (hi > N_NODES) hi = N_NODES;
    int s = 0;
    for (int i = lo; i < hi; ++i) s += counts[i];
    partial[t] = s;
    __syncthreads();
    for (int off = 1; off < 1024; off <<= 1) {
        int v = (t >= off) ? partial[t - off] : 0;
        __syncthreads();
        partial[t] += v;
        __syncthreads();
    }
    int run = (t == 0) ? 0 : partial[t - 1];
    for (int i = lo; i < hi; ++i) {
        int c = counts[i];
        offsets[i] = run;
        cursor[i]  = run;
        run += c;
    }
    if (t == 1023) offsets[N_NODES] = run;  // == N_EDGES
}

__global__ void scatter_edges_kernel(const int4* __restrict__ src4, const int4* __restrict__ dst4,
                                     int* __restrict__ cursor, int* __restrict__ srcsort) {
    int e4 = blockIdx.x * blockDim.x + threadIdx.x;
    if (e4 < N_EDGES / 4) {
        int4 s = src4[e4];
        int4 d = dst4[e4];
        srcsort[atomicAdd(&cursor[d.x], 1)] = s.x;
        srcsort[atomicAdd(&cursor[d.y], 1)] = s.y;
        srcsort[atomicAdd(&cursor[d.z], 1)] = s.z;
        srcsort[atomicAdd(&cursor[d.w], 1)] = s.w;
    }
}

// ---------------- per-layer: aggregation  x[i] = h[i] + sum_{j->i} h[j] ----------------
// Feature-sliced: block = one (node, slice of 32 floats). Slice is derived from
// blockIdx%8 so each slice's 2.56 MB line set stays resident in one XCD-pair's L2
// (perf heuristic only; correct under any dispatch mapping).
// 64 threads = 8 edge-slots x 8 lanes x float4 (128 B line per gather).

__global__ __launch_bounds__(64) void agg_slice_kernel(const float* __restrict__ hin,
                                                       const int* __restrict__ offsets,
                                                       const int* __restrict__ srcsort,
                                                       float* __restrict__ x) {
    int bid  = blockIdx.x;
    int xcd  = bid & 7;
    int q    = bid >> 3;
    int slice = xcd >> 1;            // 0..3
    int node  = q * 2 + (xcd & 1);   // 0..19999
    int t    = threadIdx.x;          // 0..63
    int slot = t >> 3;               // 0..7
    int fl   = t & 7;                // float4 index within slice
    int lo = offsets[node];
    int hi = offsets[node + 1];
    const float4* base = (const float4*)hin;   // row stride = 32 float4
    int soff = slice * 8 + fl;

    float4 a0 = make_float4(0.f, 0.f, 0.f, 0.f);
    float4 a1 = a0;

    int k = lo + slot;
    for (; k + 8 < hi; k += 16) {     // 2 gathers in flight per slot
        int s0 = srcsort[k];
        int s1 = srcsort[k + 8];
        float4 v0 = base[(size_t)s0 * 32 + soff];
        float4 v1 = base[(size_t)s1 * 32 + soff];
        a0.x += v0.x; a0.y += v0.y; a0.z += v0.z; a0.w += v0.w;
        a1.x += v1.x; a1.y += v1.y; a1.z += v1.z; a1.w += v1.w;
    }
    if (k < hi) {
        int s0 = srcsort[k];
        float4 v0 = base[(size_t)s0 * 32 + soff];
        a0.x += v0.x; a0.y += v0.y; a0.z += v0.z; a0.w += v0.w;
    }

    float4 acc;
    acc.x = a0.x + a1.x; acc.y = a0.y + a1.y;
    acc.z = a0.z + a1.z; acc.w = a0.w + a1.w;

    // reduce across the 8 slots (lanes t, t^8, t^16, t^32)
    acc.x += __shfl_xor(acc.x, 8);  acc.y += __shfl_xor(acc.y, 8);
    acc.z += __shfl_xor(acc.z, 8);  acc.w += __shfl_xor(acc.w, 8);
    acc.x += __shfl_xor(acc.x, 16); acc.y += __shfl_xor(acc.y, 16);
    acc.z += __shfl_xor(acc.z, 16); acc.w += __shfl_xor(acc.w, 16);
    acc.x += __shfl_xor(acc.x, 32); acc.y += __shfl_xor(acc.y, 32);
    acc.z += __shfl_xor(acc.z, 32); acc.w += __shfl_xor(acc.w, 32);

    if (t < 8) {
        float4 sv = base[(size_t)node * 32 + soff];   // self row (1+eps, eps=0)
        acc.x += sv.x; acc.y += sv.y; acc.z += sv.z; acc.w += sv.w;
        ((float4*)x)[(size_t)node * 32 + soff] = acc;
    }
}

// ---------------- per-layer: out = x @ W + b  (x: N x 128, W: 128 x 128) ----------------
// All inner-loop values are NAMED SCALARS (no runtime-indexable arrays -> no scratch).

__global__ __launch_bounds__(256) void gemm_kernel(const float* __restrict__ x,
                                                   const float* __restrict__ W,
                                                   const float* __restrict__ bias,
                                                   float* __restrict__ out) {
    __shared__ float Xs[TM][D];  // 32 KB
    int t = threadIdx.x;
    int row0 = blockIdx.x * TM;
    int nrows = N_NODES - row0; if (nrows > TM) nrows = TM;

    for (int i = t; i < nrows * (D / 4); i += 256) {
        int r  = i / (D / 4);
        int c4 = i % (D / 4);
        ((float4*)&Xs[r][0])[c4] = ((const float4*)&x[(size_t)(row0 + r) * D])[c4];
    }
    __syncthreads();

    int cg = t & 31;   // 32 col-groups of 4 cols
    int rg = t >> 5;   // 8 row-groups of 8 rows
    int j0 = cg * 4;
    int r0 = rg * 8;

    float acc[8][4];
    float4 bb = *((const float4*)&bias[j0]);
    #pragma unroll
    for (int i = 0; i < 8; ++i) {
        acc[i][0] = bb.x; acc[i][1] = bb.y; acc[i][2] = bb.z; acc[i][3] = bb.w;
    }

    for (int k4 = 0; k4 < D; k4 += 4) {
        float4 w0 = *((const float4*)&W[(k4 + 0) * D + j0]);
        float4 w1 = *((const float4*)&W[(k4 + 1) * D + j0]);
        float4 w2 = *((const float4*)&W[(k4 + 2) * D + j0]);
        float4 w3 = *((const float4*)&W[(k4 + 3) * D + j0]);
        #pragma unroll
        for (int i = 0; i < 8; ++i) {
            float4 xv = *((const float4*)&Xs[r0 + i][k4]);  // ds_read_b128
            acc[i][0] += xv.x * w0.x; acc[i][0] += xv.y * w1.x;
            acc[i][0] += xv.z * w2.x; acc[i][0] += xv.w * w3.x;
            acc[i][1] += xv.x * w0.y; acc[i][1] += xv.y * w1.y;
            acc[i][1] += xv.z * w2.y; acc[i][1] += xv.w * w3.y;
            acc[i][2] += xv.x * w0.z; acc[i][2] += xv.y * w1.z;
            acc[i][2] += xv.z * w2.z; acc[i][2] += xv.w * w3.z;
            acc[i][3] += xv.x * w0.w; acc[i][3] += xv.y * w1.w;
            acc[i][3] += xv.z * w2.w; acc[i][3] += xv.w * w3.w;
        }
    }

    #pragma unroll
    for (int i = 0; i < 8; ++i) {
        int r = r0 + i;
        if (r < nrows) {
            *((float4*)&out[(size_t)(row0 + r) * D + j0]) =
                make_float4(acc[i][0], acc[i][1], acc[i][2], acc[i][3]);
        }
    }
}

// ---------------- launch ----------------

extern "C" void kernel_launch(void* const* d_in, const int* in_sizes, int n_in,
                              void* d_out, int out_size, void* d_ws, size_t ws_size,
                              hipStream_t stream) {
    const float* h   = (const float*)d_in[0];
    const int*   ei  = (const int*)d_in[1];
    const int*   src = ei;
    const int*   dst = ei + N_EDGES;
    const float* Wm[4] = {(const float*)d_in[2], (const float*)d_in[4],
                          (const float*)d_in[6], (const float*)d_in[8]};
    const float* Bv[4] = {(const float*)d_in[3], (const float*)d_in[5],
                          (const float*)d_in[7], (const float*)d_in[9]};
    float* out = (float*)d_out;

    char* ws = (char*)d_ws;
    auto alloc = [&](size_t bytes) {
        char* p = ws;
        ws += (bytes + 255) & ~(size_t)255;
        return p;
    };
    int*   counts  = (int*)alloc(N_NODES * sizeof(int));
    int*   offsets = (int*)alloc((N_NODES + 1) * sizeof(int));
    int*   cursor  = (int*)alloc(N_NODES * sizeof(int));
    int*   srcsort = (int*)alloc(N_EDGES * sizeof(int));
    float* bufA    = (float*)alloc((size_t)N_NODES * D * sizeof(float));
    float* bufB    = (float*)alloc((size_t)N_NODES * D * sizeof(float));

    zero_counts_kernel<<<(N_NODES + 255) / 256, 256, 0, stream>>>(counts);
    count_deg_kernel<<<(N_EDGES / 4 + 255) / 256, 256, 0, stream>>>((const int4*)dst, counts);
    scan_offsets_kernel<<<1, 1024, 0, stream>>>(counts, offsets, cursor);
    scatter_edges_kernel<<<(N_EDGES / 4 + 255) / 256, 256, 0, stream>>>(
        (const int4*)src, (const int4*)dst, cursor, srcsort);

    const float* cur = h;
    for (int l = 0; l < 4; ++l) {
        agg_slice_kernel<<<(N_NODES / 2) * 8, 64, 0, stream>>>(cur, offsets, srcsort, bufA);
        float* o = (l == 3) ? out : bufB;
        gemm_kernel<<<(N_NODES + TM - 1) / TM, 256, 0, stream>>>(bufA, Wm[l], Bv[l], o);
        cur = o;
    }
}